// Round 8
// baseline (808.673 us; speedup 1.0000x reference)
//
#include <hip/hip_runtime.h>
#include <hip/hip_cooperative_groups.h>
#include <cfloat>
#include <cmath>

namespace cg = cooperative_groups;

#define NP 10000
#define NG 1000
#define NC 80
#define LMAX 6
#define NCH 2
#define CHSZ (NP / NCH)

// scal[]: [12] anymulti (persistent), [14] nprior, [16+t] body-ran flag
#define S_MULTI 12
#define S_NPRI  14
#define S_BODY  16
#define RI_BIG  0x3fffffff

__device__ __forceinline__ bool lexless(float av, int ai, float bv, int bi) {
    return (av < bv) || (av == bv && ai < bi);
}

// Exact sequential +1e5 inflation (reference adds 1e5 once per loop iter).
__device__ __forceinline__ float inflate(float c, int k) {
    for (int q = 0; q < k; q++) c += 100000.0f;
    return c;
}

// clsval gather for row-direction scans (column-major [NC][NP] table).
__device__ __forceinline__ float cls_at(const float* clsval,
        const int* glab, int jj, int row) {
    return clsval[(size_t)glab[jj] * NP + row];
}

// Per-pair cost+iou from precomputed tables. Contraction OFF so every kernel
// that recomputes cost(i,j) agrees bit-exactly.
__device__ __forceinline__ void cost_iou(float4 p, float4 pn, float4 pi,
        float4 g, float4 cb, float4 Gn, float ga, float clsv,
        float& cc_out, float& iou_out) {
#pragma clang fp contract(off)
    float wx = fminf(p.z, g.z) - fmaxf(p.x, g.x); wx = fmaxf(wx, 0.0f);
    float wy = fminf(p.w, g.w) - fmaxf(p.y, g.y); wy = fmaxf(wy, 0.0f);
    float inter = wx * wy;
    float uni = pi.z + ga - inter;
    float iou = inter / fmaxf(uni, 1e-12f);
    float ex = fmaxf(p.z, g.z) - fminf(p.x, g.x); ex = fmaxf(ex, 0.0f);
    float ey = fmaxf(p.w, g.w) - fminf(p.y, g.y); ey = fmaxf(ey, 0.0f);
    float enc = ex * ey;
    float giou = iou - (enc - uni) / fmaxf(enc, 1e-12f);
    float l1 = ((fabsf(pn.x - Gn.x) + fabsf(pn.y - Gn.y))
                + fabsf(pn.z - Gn.z)) + fabsf(pn.w - Gn.w);
    float cc = clsv + l1 * 5.0f;
    cc = cc + (-giou * 2.0f);
    bool inb = (pi.x > g.x && pi.x < g.z && pi.y > g.y && pi.y < g.w);
    bool inc = (pi.x > cb.x && pi.x < cb.z && pi.y > cb.y && pi.y < cb.w);
    cc = cc + ((inb && inc) ? 0.0f : 100.0f);
    cc = cc + pi.w;
    cc_out = cc; iou_out = iou;
}

// ---------------------------------------------------------------------------
// Fused prep (unchanged from R5/R6). Block ranges:
//  [0,40): init state; [40,197): cls table; [197,201): per-gt tables;
//  [201,2701): wave-per-pred validity + per-pred tables
// ---------------------------------------------------------------------------
#define CLS_TI 64
#define PB_CLS0 40
#define PB_G0   197
#define PB_V0   201
__global__ __launch_bounds__(256) void k_prep(const float* __restrict__ logits,
        const float* __restrict__ pb, const float* __restrict__ gb,
        const int* __restrict__ imgw, const int* __restrict__ imgh,
        float* __restrict__ clsval, float4* __restrict__ pnorm,
        float4* __restrict__ pinfo, float4* __restrict__ gcb,
        float4* __restrict__ gnm, float* __restrict__ gar,
        int* rowcnt, int* rowfirst, int* rowiter, int* prior, int* priorcol,
        int* colsum, int* scal)
{
    __shared__ float sl[CLS_TI * (NC + 1)];
    int b = blockIdx.x;
    if (b < PB_CLS0) {
        int i = b * 256 + threadIdx.x;
        if (i < NP) {
            rowcnt[i] = 0; rowfirst[i] = 0x7fffffff; rowiter[i] = RI_BIG;
            prior[i] = 0; priorcol[i] = 0;
        }
        if (i < NG) colsum[i] = 0;
        if (i < 32) scal[i] = 0;
    } else if (b < PB_G0) {
        int i0 = (b - PB_CLS0) * CLS_TI;
        bool full = (i0 + CLS_TI) <= NP;
        if (full) {
            const float* src = logits + (size_t)i0 * NC;
            for (int e = threadIdx.x; e < CLS_TI * NC; e += 256) {
                int di = e / NC, c = e - di * NC;
                sl[di * (NC + 1) + c] = src[e];
            }
        } else {
            for (int e = threadIdx.x; e < CLS_TI * NC; e += 256) {
                int di = e / NC, c = e - di * NC;
                int i = i0 + di;
                sl[di * (NC + 1) + c] = (i < NP) ? logits[(size_t)i * NC + c] : 0.0f;
            }
        }
        __syncthreads();
        for (int e = threadIdx.x; e < CLS_TI * NC; e += 256) {
            int c = e >> 6, di = e & 63;
            int i = i0 + di;
            if (i >= NP) continue;
            float x = sl[di * (NC + 1) + c];
            float p = 1.0f / (1.0f + expf(-x));
            float neg = -log1pf(-(p - 1e-12f)) * 0.75f * (p * p);
            float om = 1.0f - p;
            float pos = -logf(p + 1e-12f) * 0.25f * (om * om);
            clsval[(size_t)c * NP + i] = (pos - neg) * 2.0f;   // * CLS_W
        }
    } else if (b < PB_V0) {
#pragma clang fp contract(off)
        int j = (b - PB_G0) * 256 + threadIdx.x;
        if (j < NG) {
            float fw = (float)imgw[0], fh = (float)imgh[0];
            float4 g = ((const float4*)gb)[j];
            float gcx = (g.x + g.z) * 0.5f, gcy = (g.y + g.w) * 0.5f;
            float gw = g.z - g.x, gh = g.w - g.y;
            float4 cb; cb.x = gcx - 2.5f * gw; cb.y = gcy - 2.5f * gh;
            cb.z = gcx + 2.5f * gw; cb.w = gcy + 2.5f * gh;
            gcb[j] = cb;
            float4 Gn; Gn.x = g.x / fw; Gn.y = g.y / fh; Gn.z = g.z / fw; Gn.w = g.w / fh;
            gnm[j] = Gn;
            gar[j] = (g.z - g.x) * (g.w - g.y);
        }
    } else {
#pragma clang fp contract(off)
        int wave = threadIdx.x >> 6;
        int lane = threadIdx.x & 63;
        int i = (b - PB_V0) * 4 + wave;
        if (i >= NP) return;
        float4 p = ((const float4*)pb)[i];
        float pcx = (p.x + p.z) * 0.5f, pcy = (p.y + p.w) * 0.5f;
        int vb = 0, vc = 0;
        const float4* gb4 = (const float4*)gb;
        for (int j = lane; j < NG; j += 64) {
            float4 g = gb4[j];
            vb |= (pcx > g.x && pcx < g.z && pcy > g.y && pcy < g.w) ? 1 : 0;
            float gcx = (g.x + g.z) * 0.5f, gcy = (g.y + g.w) * 0.5f;
            float gw = g.z - g.x, gh = g.w - g.y;
            vc |= (pcx > gcx - 2.5f * gw && pcx < gcx + 2.5f * gw &&
                   pcy > gcy - 2.5f * gh && pcy < gcy + 2.5f * gh) ? 1 : 0;
        }
        int any = (__any(vb) ? 1 : 0) | (__any(vc) ? 1 : 0);
        if (lane == 0) {
            float fw = (float)imgw[0], fh = (float)imgh[0];
            float4 pn; pn.x = p.x / fw; pn.y = p.y / fh; pn.z = p.z / fw; pn.w = p.w / fh;
            pnorm[i] = pn;
            float4 pi4; pi4.x = pcx; pi4.y = pcy;
            pi4.z = (p.z - p.x) * (p.w - p.y);
            pi4.w = any ? 0.0f : 10000.0f;
            pinfo[i] = pi4;
        }
    }
}

// compare-exchange helpers for 5-element sorting networks
__device__ __forceinline__ void ce_lex(float* v, int* x, int a, int b) {
    if (lexless(v[b], x[b], v[a], x[a])) {
        float tv = v[a]; v[a] = v[b]; v[b] = tv;
        int ti = x[a]; x[a] = x[b]; x[b] = ti;
    }
}
__device__ __forceinline__ void ce_desc(float* v, int a, int b) {
    if (v[b] > v[a]) { float tv = v[a]; v[a] = v[b]; v[b] = tv; }
}

// ---------------------------------------------------------------------------
// k_cost2: block (j, chunk c) scans preds [c*5000,(c+1)*5000). Per-thread
// UNSORTED top-5 with cached lex-worst (cheap check), sort-once at end,
// then stride-7 LDS merge tree -> 5-entry sorted partials.
// ---------------------------------------------------------------------------
__global__ __launch_bounds__(256) void k_cost2(
        const float* __restrict__ pb, const float* __restrict__ gb,
        const int* __restrict__ glab, const float* __restrict__ clsval,
        const float4* __restrict__ pnorm, const float4* __restrict__ pinfo,
        const float4* __restrict__ gcb, const float4* __restrict__ gnm,
        const float* __restrict__ gar,
        float* __restrict__ pcv, int* __restrict__ pci, float* __restrict__ piv)
{
    __shared__ float s_cv[256 * 7];
    __shared__ int   s_ci[256 * 7];
    __shared__ float s_iv[256 * 7];

    int j = blockIdx.x >> 1;
    int c = blockIdx.x & 1;
    float4 g  = ((const float4*)gb)[j];
    float4 cb = gcb[j];
    float4 Gn = gnm[j];
    float  ga = gar[j];
    const float* clscol = clsval + (size_t)glab[j] * NP;
    const float4* pb4 = (const float4*)pb;

    float cv[5]; int ci[5]; float iv[5];
#pragma unroll
    for (int t = 0; t < 5; t++) { cv[t] = FLT_MAX; ci[t] = 0x7fffffff; iv[t] = -1.0f; }
    float wv = FLT_MAX; int wi = 0x7fffffff; int wslot = 0;   // lex-worst of cv set
    float mn = -1.0f; int mslot = 0;                          // min of iv set

    int iend = (c + 1) * CHSZ;
    for (int i = c * CHSZ + threadIdx.x; i < iend; i += 256) {
        float cc, iou;
        cost_iou(pb4[i], pnorm[i], pinfo[i], g, cb, Gn, ga, clscol[i], cc, iou);

        if (lexless(cc, i, wv, wi)) {
#pragma unroll
            for (int t = 0; t < 5; t++) if (t == wslot) { cv[t] = cc; ci[t] = i; }
            wv = cv[0]; wi = ci[0]; wslot = 0;
#pragma unroll
            for (int t = 1; t < 5; t++)
                if (lexless(wv, wi, cv[t], ci[t])) { wv = cv[t]; wi = ci[t]; wslot = t; }
        }
        if (iou > mn) {
#pragma unroll
            for (int t = 0; t < 5; t++) if (t == mslot) iv[t] = iou;
            mn = iv[0]; mslot = 0;
#pragma unroll
            for (int t = 1; t < 5; t++)
                if (iv[t] < mn) { mn = iv[t]; mslot = t; }
        }
    }

    // sort cv/ci lex-ascending, iv descending (9-CE optimal network)
    ce_lex(cv, ci, 0, 1); ce_lex(cv, ci, 3, 4); ce_lex(cv, ci, 2, 4);
    ce_lex(cv, ci, 2, 3); ce_lex(cv, ci, 1, 4); ce_lex(cv, ci, 0, 3);
    ce_lex(cv, ci, 0, 2); ce_lex(cv, ci, 1, 3); ce_lex(cv, ci, 1, 2);
    ce_desc(iv, 0, 1); ce_desc(iv, 3, 4); ce_desc(iv, 2, 4);
    ce_desc(iv, 2, 3); ce_desc(iv, 1, 4); ce_desc(iv, 0, 3);
    ce_desc(iv, 0, 2); ce_desc(iv, 1, 3); ce_desc(iv, 1, 2);

    int base = threadIdx.x * 7;
#pragma unroll
    for (int t = 0; t < 5; t++) { s_cv[base+t] = cv[t]; s_ci[base+t] = ci[t]; s_iv[base+t] = iv[t]; }
    s_cv[base+5] = FLT_MAX; s_ci[base+5] = 0x7fffffff; s_iv[base+5] = -2.0f;
    __syncthreads();

    for (int w = 128; w > 0; w >>= 1) {
        if (threadIdx.x < (unsigned)w) {
            int a = threadIdx.x * 7, bb = (threadIdx.x + w) * 7;
            float ov[5]; int oi[5]; float og[5];
            int pa = a, pbp = bb;
#pragma unroll
            for (int t = 0; t < 5; t++) {
                float A = s_cv[pa], B = s_cv[pbp];
                int Ai = s_ci[pa], Bi = s_ci[pbp];
                bool tA = (A < B) || (A == B && Ai <= Bi);
                if (tA) { ov[t] = A; oi[t] = Ai; pa++; } else { ov[t] = B; oi[t] = Bi; pbp++; }
            }
            int qa = a, qb = bb;
#pragma unroll
            for (int t = 0; t < 5; t++) {
                float A = s_iv[qa], B = s_iv[qb];
                if (A >= B) { og[t] = A; qa++; } else { og[t] = B; qb++; }
            }
#pragma unroll
            for (int t = 0; t < 5; t++) { s_cv[a+t] = ov[t]; s_ci[a+t] = oi[t]; s_iv[a+t] = og[t]; }
        }
        __syncthreads();
    }

    if (threadIdx.x == 0) {
        int ob = blockIdx.x * 5;
#pragma unroll
        for (int t = 0; t < 5; t++) {
            pcv[ob + t] = s_cv[t]; pci[ob + t] = s_ci[t]; piv[ob + t] = s_iv[t];
        }
    }
}

// ---------------------------------------------------------------------------
// k_coop: ONE cooperative kernel (grid = NG blocks x 256) doing:
//  phase0 merge partials -> dk/picks/row atomics
//  phase1 pscan+surv, then pfix (prior-row argmin)
//  phase2 the LMAX loop (B: unmatched-column argmin over uninflated rows;
//          C: m_fix on prior rows with exact sequential inflation)
//  phase3 final output
// ---------------------------------------------------------------------------
__global__ __launch_bounds__(256) void k_coop(
        const float* __restrict__ pb, const float* __restrict__ gb,
        const int* __restrict__ glab, const float* __restrict__ clsval,
        const float4* __restrict__ pnorm, const float4* __restrict__ pinfo,
        const float4* __restrict__ gcb, const float4* __restrict__ gnm,
        const float* __restrict__ gar,
        const float* __restrict__ pcv, const int* __restrict__ pci,
        const float* __restrict__ piv,
        int* rowcnt, int* rowfirst, int* rowiter, int* prior, int* priorcol,
        int* plist, int* picks, int* dkarr, int* colsum, int* scal, int* out)
{
    cg::grid_group grid = cg::this_grid();
    __shared__ float rv[256]; __shared__ int ri[256];
    int bj = blockIdx.x;
    int tid = threadIdx.x;
    int gid = bj * 256 + tid;
    const float4* pb4 = (const float4*)pb;
    const float4* gb4 = (const float4*)gb;
    volatile int* vscal = (volatile int*)scal;

    // ---- phase 0: merge the 2 sorted 5-lists for column bj ----
    if (tid == 0) {
        int base = bj * 2 * 5;
        int h0 = 0, h1 = 0;
        int besti[5];
#pragma unroll
        for (int r = 0; r < 5; r++) {
            float v0 = (h0 < 5) ? pcv[base + h0] : FLT_MAX;
            int   i0 = (h0 < 5) ? pci[base + h0] : 0x7fffffff;
            float v1 = (h1 < 5) ? pcv[base + 5 + h1] : FLT_MAX;
            int   i1 = (h1 < 5) ? pci[base + 5 + h1] : 0x7fffffff;
            if (lexless(v0, i0, v1, i1)) { besti[r] = i0; h0++; }
            else                          { besti[r] = i1; h1++; }
        }
        int g0 = 0, g1 = 0;
        float ivm[5];
#pragma unroll
        for (int r = 0; r < 5; r++) {
            float v0 = (g0 < 5) ? piv[base + g0] : -FLT_MAX;
            float v1 = (g1 < 5) ? piv[base + 5 + g1] : -FLT_MAX;
            if (v0 >= v1) { ivm[r] = v0; g0++; } else { ivm[r] = v1; g1++; }
        }
        float s = (((ivm[0] + ivm[1]) + ivm[2]) + ivm[3]) + ivm[4];
        int dk = (int)s;                 // astype(int32): truncation
        if (dk < 1) dk = 1;
        dkarr[bj] = dk;
        for (int t = 0; t < dk; t++) {
            int r = besti[t];
            picks[bj * 5 + t] = r;
            atomicAdd(&rowcnt[r], 1);
            atomicMin(&rowfirst[r], bj);
            atomicMin(&rowiter[r], -1);   // initially matched
        }
    }
    grid.sync();

    // ---- phase 1a: pscan + surv ----
    if (gid < NP) {
        if (rowcnt[gid] > 1) {
            prior[gid] = 1;
            int idx = atomicAdd(&scal[S_NPRI], 1);
            plist[idx] = gid;
        }
    }
    if (tid == 0) {
        int dk = dkarr[bj], c = 0;
        for (int t = 0; t < dk; t++) if (rowcnt[picks[bj * 5 + t]] == 1) c++;
        if (c) atomicAdd(&colsum[bj], c);
    }
    grid.sync();

    int nprior = vscal[S_NPRI];

    // ---- phase 1b: pfix — prior rows strided over blocks ----
    for (int pr = bj; pr < nprior; pr += NG) {
        int row = plist[pr];
        float4 p = pb4[row];
        float4 pn = pnorm[row];
        float4 pi4 = pinfo[row];
        float best = FLT_MAX; int bjx = 0x7fffffff;
        for (int jj = tid; jj < NG; jj += 256) {
            float cc, iou;
            cost_iou(p, pn, pi4, gb4[jj], gcb[jj], gnm[jj], gar[jj],
                     cls_at(clsval, glab, jj, row), cc, iou);
            if (lexless(cc, jj, best, bjx)) { best = cc; bjx = jj; }
        }
        rv[tid] = best; ri[tid] = bjx; __syncthreads();
        for (int w = 128; w > 0; w >>= 1) {
            if (tid < w) {
                float ov = rv[tid + w]; int oi = ri[tid + w];
                if (lexless(ov, oi, rv[tid], ri[tid])) { rv[tid] = ov; ri[tid] = oi; }
            }
            __syncthreads();
        }
        if (tid == 0) {
            priorcol[row] = ri[0];
            atomicAdd(&colsum[ri[0]], 1);
        }
        __syncthreads();
    }
    grid.sync();

    // ---- phase 2: the while-loop ----
    for (int t = 0; t < LMAX; t++) {
        // B: unmatched columns argmin over uninflated rows
        if (((volatile int*)colsum)[bj] == 0) {
            if (tid == 0) atomicOr(&scal[S_BODY + t], 1);
            float4 g  = gb4[bj];
            float4 cbv = gcb[bj];
            float4 Gn = gnm[bj];
            float  ga = gar[bj];
            const float* clscol = clsval + (size_t)glab[bj] * NP;
            float best = FLT_MAX; int bi = 0x7fffffff;
            for (int i = tid; i < NP; i += 256) {
                if (rowiter[i] < t) continue;   // inflated row: strictly dominated
                float cc, iou;
                cost_iou(pb4[i], pnorm[i], pinfo[i], g, cbv, Gn, ga, clscol[i], cc, iou);
                if (lexless(cc, i, best, bi)) { best = cc; bi = i; }
            }
            rv[tid] = best; ri[tid] = bi; __syncthreads();
            for (int w = 128; w > 0; w >>= 1) {
                if (tid < w) {
                    float ov = rv[tid + w]; int oi = ri[tid + w];
                    if (lexless(ov, oi, rv[tid], ri[tid])) { rv[tid] = ov; ri[tid] = oi; }
                }
                __syncthreads();
            }
            if (tid == 0) {
                int pos = ri[0];
                atomicExch(&colsum[bj], 1);
                int old = atomicAdd(&rowcnt[pos], 1);
                if (old >= 1) atomicOr(&scal[S_MULTI], 1);   // same-iter collision
                atomicMin(&rowfirst[pos], bj);
                atomicMin(&rowiter[pos], t);
            }
        }
        grid.sync();
        if (vscal[S_BODY + t] == 0) break;   // converged (uniform across grid)

        // C: m_fix on prior rows with exact sequential inflation
        if (vscal[S_MULTI] != 0) {
            for (int pr = bj; pr < nprior; pr += NG) {
                int row = plist[pr];
                int k = t - rowiter[row]; if (k < 0) k = 0;   // prior rows: -1 -> t+1
                float4 p = pb4[row];
                float4 pn = pnorm[row];
                float4 pi4 = pinfo[row];
                float best = FLT_MAX; int bjx = 0x7fffffff;
                for (int jj = tid; jj < NG; jj += 256) {
                    float cc, iou;
                    cost_iou(p, pn, pi4, gb4[jj], gcb[jj], gnm[jj], gar[jj],
                             cls_at(clsval, glab, jj, row), cc, iou);
                    float val = inflate(cc, k);
                    if (lexless(val, jj, best, bjx)) { best = val; bjx = jj; }
                }
                rv[tid] = best; ri[tid] = bjx; __syncthreads();
                for (int w = 128; w > 0; w >>= 1) {
                    if (tid < w) {
                        float ov = rv[tid + w]; int oi = ri[tid + w];
                        if (lexless(ov, oi, rv[tid], ri[tid])) { rv[tid] = ov; ri[tid] = oi; }
                    }
                    __syncthreads();
                }
                if (tid == 0) {
                    int nb = ri[0];
                    int oldc = priorcol[row];
                    if (nb != oldc) {
                        atomicSub(&colsum[oldc], 1);
                        atomicAdd(&colsum[nb], 1);
                        priorcol[row] = nb;
                    }
                }
                __syncthreads();
            }
        }
        grid.sync();
    }

    // ---- phase 3: final ----
    if (gid < NP) {
        int fg = rowcnt[gid] > 0;
        out[gid] = fg ? 1 : 0;
        out[NP + gid] = fg ? (prior[gid] ? priorcol[gid] : rowfirst[gid]) : 0;
    }
}

extern "C" void kernel_launch(void* const* d_in, const int* in_sizes, int n_in,
                              void* d_out, int out_size, void* d_ws, size_t ws_size,
                              hipStream_t stream)
{
    (void)in_sizes; (void)n_in; (void)out_size; (void)ws_size;
    const float* logits = (const float*)d_in[0];
    const float* pboxes = (const float*)d_in[1];
    const float* gboxes = (const float*)d_in[2];
    const int*   glab   = (const int*)d_in[3];
    const int*   imgh   = (const int*)d_in[4];
    const int*   imgw   = (const int*)d_in[5];
    int* out = (int*)d_out;

    char* w = (char*)d_ws;
    float*  clsval  = (float*)(w);                    // 3,200,000
    float4* pnorm   = (float4*)(w + 3200000);         //   160,000
    float4* pinfo   = (float4*)(w + 3360000);         //   160,000
    float4* gcb     = (float4*)(w + 3520000);         //    16,000
    float4* gnm     = (float4*)(w + 3536000);         //    16,000
    float*  gar     = (float*)(w + 3552000);          //     4,000
    int* rowcnt     = (int*)(w + 3556000);            //    40,000
    int* rowfirst   = (int*)(w + 3596000);            //    40,000
    int* rowiter    = (int*)(w + 3636000);            //    40,000
    int* prior      = (int*)(w + 3676000);            //    40,000
    int* priorcol   = (int*)(w + 3716000);            //    40,000
    int* plist      = (int*)(w + 3756000);            //    40,000
    int* picks      = (int*)(w + 3796000);            //    20,000
    int* dkarr      = (int*)(w + 3816000);            //     4,000
    int* colsum     = (int*)(w + 3820000);            //     4,000
    int* scal       = (int*)(w + 3824000);            //       128
    float* pcv      = (float*)(w + 3824128);          //    40,000
    int*   pci      = (int*)(w + 3864128);            //    40,000
    float* piv      = (float*)(w + 3904128);          //    40,000

    hipLaunchKernelGGL(k_prep, dim3(2701), dim3(256), 0, stream,
                       logits, pboxes, gboxes, imgw, imgh,
                       clsval, pnorm, pinfo, gcb, gnm, gar,
                       rowcnt, rowfirst, rowiter, prior, priorcol, colsum, scal);
    hipLaunchKernelGGL(k_cost2, dim3(NG * NCH), dim3(256), 0, stream,
                       pboxes, gboxes, glab, clsval, pnorm, pinfo, gcb, gnm, gar,
                       pcv, pci, piv);

    void* args[] = {
        (void*)&pboxes, (void*)&gboxes, (void*)&glab, (void*)&clsval,
        (void*)&pnorm, (void*)&pinfo, (void*)&gcb, (void*)&gnm, (void*)&gar,
        (void*)&pcv, (void*)&pci, (void*)&piv,
        (void*)&rowcnt, (void*)&rowfirst, (void*)&rowiter, (void*)&prior,
        (void*)&priorcol, (void*)&plist, (void*)&picks, (void*)&dkarr,
        (void*)&colsum, (void*)&scal, (void*)&out
    };
    hipError_t err = hipLaunchCooperativeKernel((void*)k_coop, dim3(NG), dim3(256),
                                                args, 0, stream);
    (void)err;
}

// Round 9
// 198.721 us; speedup vs baseline: 4.0694x; 4.0694x over previous
//
#include <hip/hip_runtime.h>
#include <cfloat>
#include <cmath>

#define NP 10000
#define NG 1000
#define NC 80
#define LMAX 6
#define NCH 2
#define CHSZ (NP / NCH)

// scal[]: [12] anymulti (persistent), [14] nprior, [16+t] body-ran flag
#define S_MULTI 12
#define S_NPRI  14
#define S_BODY  16
#define RI_BIG  0x3fffffff

__device__ __forceinline__ bool lexless(float av, int ai, float bv, int bi) {
    return (av < bv) || (av == bv && ai < bi);
}

// Exact sequential +1e5 inflation (reference adds 1e5 once per loop iter).
__device__ __forceinline__ float inflate(float c, int k) {
    for (int q = 0; q < k; q++) c += 100000.0f;
    return c;
}

// Per-pair cost+iou from precomputed tables. Contraction OFF so every kernel
// that recomputes cost(i,j) agrees bit-exactly.
__device__ __forceinline__ void cost_iou(float4 p, float4 pn, float4 pi,
        float4 g, float4 cb, float4 Gn, float ga, float clsv,
        float& cc_out, float& iou_out) {
#pragma clang fp contract(off)
    float wx = fminf(p.z, g.z) - fmaxf(p.x, g.x); wx = fmaxf(wx, 0.0f);
    float wy = fminf(p.w, g.w) - fmaxf(p.y, g.y); wy = fmaxf(wy, 0.0f);
    float inter = wx * wy;
    float uni = pi.z + ga - inter;
    float iou = inter / fmaxf(uni, 1e-12f);
    float ex = fmaxf(p.z, g.z) - fminf(p.x, g.x); ex = fmaxf(ex, 0.0f);
    float ey = fmaxf(p.w, g.w) - fminf(p.y, g.y); ey = fmaxf(ey, 0.0f);
    float enc = ex * ey;
    float giou = iou - (enc - uni) / fmaxf(enc, 1e-12f);
    float l1 = ((fabsf(pn.x - Gn.x) + fabsf(pn.y - Gn.y))
                + fabsf(pn.z - Gn.z)) + fabsf(pn.w - Gn.w);
    float cc = clsv + l1 * 5.0f;
    cc = cc + (-giou * 2.0f);
    bool inb = (pi.x > g.x && pi.x < g.z && pi.y > g.y && pi.y < g.w);
    bool inc = (pi.x > cb.x && pi.x < cb.z && pi.y > cb.y && pi.y < cb.w);
    cc = cc + ((inb && inc) ? 0.0f : 100.0f);
    cc = cc + pi.w;
    cc_out = cc; iou_out = iou;
}

// ---------------------------------------------------------------------------
// Fused prep. Block ranges:
//  [0,40): init state; [40,197): cls table; [197,201): per-gt tables;
//  [201,2701): wave-per-pred validity + per-pred tables
// ---------------------------------------------------------------------------
#define CLS_TI 64
#define PB_CLS0 40
#define PB_G0   197
#define PB_V0   201
__global__ __launch_bounds__(256) void k_prep(const float* __restrict__ logits,
        const float* __restrict__ pb, const float* __restrict__ gb,
        const int* __restrict__ imgw, const int* __restrict__ imgh,
        float* __restrict__ clsval, float4* __restrict__ pnorm,
        float4* __restrict__ pinfo, float4* __restrict__ gcb,
        float4* __restrict__ gnm, float* __restrict__ gar,
        int* rowcnt, int* rowfirst, int* rowiter, int* prior, int* priorcol,
        int* colsum, int* scal)
{
    __shared__ float sl[CLS_TI * (NC + 1)];
    int b = blockIdx.x;
    if (b < PB_CLS0) {
        int i = b * 256 + threadIdx.x;
        if (i < NP) {
            rowcnt[i] = 0; rowfirst[i] = 0x7fffffff; rowiter[i] = RI_BIG;
            prior[i] = 0; priorcol[i] = 0;
        }
        if (i < NG) colsum[i] = 0;
        if (i < 32) scal[i] = 0;
    } else if (b < PB_G0) {
        int i0 = (b - PB_CLS0) * CLS_TI;
        bool full = (i0 + CLS_TI) <= NP;
        if (full) {
            const float* src = logits + (size_t)i0 * NC;
            for (int e = threadIdx.x; e < CLS_TI * NC; e += 256) {
                int di = e / NC, c = e - di * NC;
                sl[di * (NC + 1) + c] = src[e];
            }
        } else {
            for (int e = threadIdx.x; e < CLS_TI * NC; e += 256) {
                int di = e / NC, c = e - di * NC;
                int i = i0 + di;
                sl[di * (NC + 1) + c] = (i < NP) ? logits[(size_t)i * NC + c] : 0.0f;
            }
        }
        __syncthreads();
        for (int e = threadIdx.x; e < CLS_TI * NC; e += 256) {
            int c = e >> 6, di = e & 63;
            int i = i0 + di;
            if (i >= NP) continue;
            float x = sl[di * (NC + 1) + c];
            float p = 1.0f / (1.0f + expf(-x));
            float neg = -log1pf(-(p - 1e-12f)) * 0.75f * (p * p);
            float om = 1.0f - p;
            float pos = -logf(p + 1e-12f) * 0.25f * (om * om);
            clsval[(size_t)c * NP + i] = (pos - neg) * 2.0f;   // * CLS_W
        }
    } else if (b < PB_V0) {
#pragma clang fp contract(off)
        int j = (b - PB_G0) * 256 + threadIdx.x;
        if (j < NG) {
            float fw = (float)imgw[0], fh = (float)imgh[0];
            float4 g = ((const float4*)gb)[j];
            float gcx = (g.x + g.z) * 0.5f, gcy = (g.y + g.w) * 0.5f;
            float gw = g.z - g.x, gh = g.w - g.y;
            float4 cb; cb.x = gcx - 2.5f * gw; cb.y = gcy - 2.5f * gh;
            cb.z = gcx + 2.5f * gw; cb.w = gcy + 2.5f * gh;
            gcb[j] = cb;
            float4 Gn; Gn.x = g.x / fw; Gn.y = g.y / fh; Gn.z = g.z / fw; Gn.w = g.w / fh;
            gnm[j] = Gn;
            gar[j] = (g.z - g.x) * (g.w - g.y);
        }
    } else {
#pragma clang fp contract(off)
        int wave = threadIdx.x >> 6;
        int lane = threadIdx.x & 63;
        int i = (b - PB_V0) * 4 + wave;
        if (i >= NP) return;
        float4 p = ((const float4*)pb)[i];
        float pcx = (p.x + p.z) * 0.5f, pcy = (p.y + p.w) * 0.5f;
        int vb = 0, vc = 0;
        const float4* gb4 = (const float4*)gb;
        for (int j = lane; j < NG; j += 64) {
            float4 g = gb4[j];
            vb |= (pcx > g.x && pcx < g.z && pcy > g.y && pcy < g.w) ? 1 : 0;
            float gcx = (g.x + g.z) * 0.5f, gcy = (g.y + g.w) * 0.5f;
            float gw = g.z - g.x, gh = g.w - g.y;
            vc |= (pcx > gcx - 2.5f * gw && pcx < gcx + 2.5f * gw &&
                   pcy > gcy - 2.5f * gh && pcy < gcy + 2.5f * gh) ? 1 : 0;
        }
        int any = (__any(vb) ? 1 : 0) | (__any(vc) ? 1 : 0);
        if (lane == 0) {
            float fw = (float)imgw[0], fh = (float)imgh[0];
            float4 pn; pn.x = p.x / fw; pn.y = p.y / fh; pn.z = p.z / fw; pn.w = p.w / fh;
            pnorm[i] = pn;
            float4 pi4; pi4.x = pcx; pi4.y = pcy;
            pi4.z = (p.z - p.x) * (p.w - p.y);
            pi4.w = any ? 0.0f : 10000.0f;
            pinfo[i] = pi4;
        }
    }
}

// compare-exchange helpers for 5-element sorting networks
__device__ __forceinline__ void ce_lex(float* v, int* x, int a, int b) {
    if (lexless(v[b], x[b], v[a], x[a])) {
        float tv = v[a]; v[a] = v[b]; v[b] = tv;
        int ti = x[a]; x[a] = x[b]; x[b] = ti;
    }
}
__device__ __forceinline__ void ce_desc(float* v, int a, int b) {
    if (v[b] > v[a]) { float tv = v[a]; v[a] = v[b]; v[b] = tv; }
}

// ---------------------------------------------------------------------------
// k_cost2: block (j, chunk c) scans preds [c*5000,(c+1)*5000). Per-thread
// UNSORTED top-5 with cached lex-worst (2-cmp common path), sort-once at end,
// then stride-7 LDS merge tree -> sorted 5-entry partials per (j, chunk).
// ---------------------------------------------------------------------------
__global__ __launch_bounds__(256) void k_cost2(
        const float* __restrict__ pb, const float* __restrict__ gb,
        const int* __restrict__ glab, const float* __restrict__ clsval,
        const float4* __restrict__ pnorm, const float4* __restrict__ pinfo,
        const float4* __restrict__ gcb, const float4* __restrict__ gnm,
        const float* __restrict__ gar,
        float* __restrict__ pcv, int* __restrict__ pci, float* __restrict__ piv)
{
    __shared__ float s_cv[256 * 7];
    __shared__ int   s_ci[256 * 7];
    __shared__ float s_iv[256 * 7];

    int j = blockIdx.x >> 1;
    int c = blockIdx.x & 1;
    float4 g  = ((const float4*)gb)[j];
    float4 cb = gcb[j];
    float4 Gn = gnm[j];
    float  ga = gar[j];
    const float* clscol = clsval + (size_t)glab[j] * NP;
    const float4* pb4 = (const float4*)pb;

    float cv[5]; int ci[5]; float iv[5];
#pragma unroll
    for (int t = 0; t < 5; t++) { cv[t] = FLT_MAX; ci[t] = 0x7fffffff; iv[t] = -1.0f; }
    float wv = FLT_MAX; int wi = 0x7fffffff; int wslot = 0;   // lex-worst of cv set
    float mn = -1.0f; int mslot = 0;                          // min of iv set

    int iend = (c + 1) * CHSZ;
    for (int i = c * CHSZ + threadIdx.x; i < iend; i += 256) {
        float cc, iou;
        cost_iou(pb4[i], pnorm[i], pinfo[i], g, cb, Gn, ga, clscol[i], cc, iou);

        if (lexless(cc, i, wv, wi)) {
#pragma unroll
            for (int t = 0; t < 5; t++) if (t == wslot) { cv[t] = cc; ci[t] = i; }
            wv = cv[0]; wi = ci[0]; wslot = 0;
#pragma unroll
            for (int t = 1; t < 5; t++)
                if (lexless(wv, wi, cv[t], ci[t])) { wv = cv[t]; wi = ci[t]; wslot = t; }
        }
        if (iou > mn) {
#pragma unroll
            for (int t = 0; t < 5; t++) if (t == mslot) iv[t] = iou;
            mn = iv[0]; mslot = 0;
#pragma unroll
            for (int t = 1; t < 5; t++)
                if (iv[t] < mn) { mn = iv[t]; mslot = t; }
        }
    }

    // sort cv/ci lex-ascending, iv descending (9-CE optimal network)
    ce_lex(cv, ci, 0, 1); ce_lex(cv, ci, 3, 4); ce_lex(cv, ci, 2, 4);
    ce_lex(cv, ci, 2, 3); ce_lex(cv, ci, 1, 4); ce_lex(cv, ci, 0, 3);
    ce_lex(cv, ci, 0, 2); ce_lex(cv, ci, 1, 3); ce_lex(cv, ci, 1, 2);
    ce_desc(iv, 0, 1); ce_desc(iv, 3, 4); ce_desc(iv, 2, 4);
    ce_desc(iv, 2, 3); ce_desc(iv, 1, 4); ce_desc(iv, 0, 3);
    ce_desc(iv, 0, 2); ce_desc(iv, 1, 3); ce_desc(iv, 1, 2);

    int base = threadIdx.x * 7;
#pragma unroll
    for (int t = 0; t < 5; t++) { s_cv[base+t] = cv[t]; s_ci[base+t] = ci[t]; s_iv[base+t] = iv[t]; }
    s_cv[base+5] = FLT_MAX; s_ci[base+5] = 0x7fffffff; s_iv[base+5] = -2.0f;
    __syncthreads();

    for (int w = 128; w > 0; w >>= 1) {
        if (threadIdx.x < (unsigned)w) {
            int a = threadIdx.x * 7, bb = (threadIdx.x + w) * 7;
            float ov[5]; int oi[5]; float og[5];
            int pa = a, pbp = bb;
#pragma unroll
            for (int t = 0; t < 5; t++) {
                float A = s_cv[pa], B = s_cv[pbp];
                int Ai = s_ci[pa], Bi = s_ci[pbp];
                bool tA = (A < B) || (A == B && Ai <= Bi);
                if (tA) { ov[t] = A; oi[t] = Ai; pa++; } else { ov[t] = B; oi[t] = Bi; pbp++; }
            }
            int qa = a, qb = bb;
#pragma unroll
            for (int t = 0; t < 5; t++) {
                float A = s_iv[qa], B = s_iv[qb];
                if (A >= B) { og[t] = A; qa++; } else { og[t] = B; qb++; }
            }
#pragma unroll
            for (int t = 0; t < 5; t++) { s_cv[a+t] = ov[t]; s_ci[a+t] = oi[t]; s_iv[a+t] = og[t]; }
        }
        __syncthreads();
    }

    if (threadIdx.x == 0) {
        int ob = blockIdx.x * 5;
#pragma unroll
        for (int t = 0; t < 5; t++) {
            pcv[ob + t] = s_cv[t]; pci[ob + t] = s_ci[t]; piv[ob + t] = s_iv[t];
        }
    }
}

// ---------------------------------------------------------------------------
// Merge partials: thread per gt. Exact 2-way merge of sorted 5-lists
// (lex for cost; value-desc for iou; iou sum order matches lax.top_k output
// order). dk, picks, row atomics.
// ---------------------------------------------------------------------------
__global__ __launch_bounds__(256) void k_costmerge(
        const float* __restrict__ pcv, const int* __restrict__ pci,
        const float* __restrict__ piv,
        int* __restrict__ rowcnt, int* __restrict__ rowfirst,
        int* __restrict__ rowiter, int* __restrict__ picks,
        int* __restrict__ dkarr)
{
    int j = blockIdx.x * 256 + threadIdx.x;
    if (j >= NG) return;
    int base = j * 2 * 5;
    int h0 = 0, h1 = 0;
    int besti[5];
#pragma unroll
    for (int r = 0; r < 5; r++) {
        float v0 = pcv[base + h0];
        int   i0 = pci[base + h0];
        float v1 = pcv[base + 5 + h1];
        int   i1 = pci[base + 5 + h1];
        if (lexless(v0, i0, v1, i1)) { besti[r] = i0; h0++; }
        else                          { besti[r] = i1; h1++; }
    }
    int g0 = 0, g1 = 0;
    float ivm[5];
#pragma unroll
    for (int r = 0; r < 5; r++) {
        float v0 = piv[base + g0];
        float v1 = piv[base + 5 + g1];
        if (v0 >= v1) { ivm[r] = v0; g0++; } else { ivm[r] = v1; g1++; }
    }
    float s = (((ivm[0] + ivm[1]) + ivm[2]) + ivm[3]) + ivm[4];
    int dk = (int)s;                 // astype(int32): truncation
    if (dk < 1) dk = 1;
    dkarr[j] = dk;
    for (int t = 0; t < dk; t++) {
        int r = besti[t];
        picks[j * 5 + t] = r;
        atomicAdd(&rowcnt[r], 1);
        atomicMin(&rowfirst[r], j);
        atomicMin(&rowiter[r], -1);   // initially matched
    }
}

// ---------------------------------------------------------------------------
// Prior scan: rows with >1 initial assignment -> prior list.
// ---------------------------------------------------------------------------
__global__ __launch_bounds__(256) void k_pscan(const int* __restrict__ rowcnt,
        int* __restrict__ prior, int* __restrict__ plist, int* __restrict__ scal)
{
    int i = blockIdx.x * 256 + threadIdx.x;
    if (i >= NP) return;
    if (rowcnt[i] > 1) {
        prior[i] = 1;
        int idx = atomicAdd(&scal[S_NPRI], 1);
        plist[idx] = i;
    }
}

// ---------------------------------------------------------------------------
// Fused pfix + surv. Blocks [0,2500): per prior row, cooperative argmin over
// the row's (uninflated) cost -> priorcol, contribute to colsum.
// Blocks [2500,2504): surviving single-pick rows -> colsum.
// ---------------------------------------------------------------------------
__global__ __launch_bounds__(256) void k_pfixsurv(const float* __restrict__ pb,
        const float* __restrict__ gb, const int* __restrict__ glab,
        const float* __restrict__ clsval,
        const float4* __restrict__ pnorm, const float4* __restrict__ pinfo,
        const float4* __restrict__ gcb, const float4* __restrict__ gnm,
        const float* __restrict__ gar,
        const int* __restrict__ plist, int* __restrict__ priorcol,
        int* __restrict__ colsum, const int* __restrict__ scal,
        const int* __restrict__ rowcnt, const int* __restrict__ picks,
        const int* __restrict__ dkarr)
{
    int b = blockIdx.x;
    if (b >= 2500) {
        int j = (b - 2500) * 256 + threadIdx.x;
        if (j >= NG) return;
        int c = 0;
        int dk = dkarr[j];
        for (int t = 0; t < dk; t++) if (rowcnt[picks[j * 5 + t]] == 1) c++;
        if (c) atomicAdd(&colsum[j], c);
        return;
    }
    if (b >= scal[S_NPRI]) return;
    int row = plist[b];
    float4 p = ((const float4*)pb)[row];
    float4 pn = pnorm[row];
    float4 pi4 = pinfo[row];

    __shared__ float rv[256]; __shared__ int ri[256];
    float best = FLT_MAX; int bj = 0x7fffffff;
    for (int j = threadIdx.x; j < NG; j += 256) {
        float cc, iou;
        cost_iou(p, pn, pi4, ((const float4*)gb)[j], gcb[j], gnm[j], gar[j],
                 clsval[(size_t)glab[j] * NP + row], cc, iou);
        if (lexless(cc, j, best, bj)) { best = cc; bj = j; }
    }
    rv[threadIdx.x] = best; ri[threadIdx.x] = bj; __syncthreads();
    for (int w = 128; w > 0; w >>= 1) {
        if (threadIdx.x < (unsigned)w) {
            float ov = rv[threadIdx.x + w]; int oi = ri[threadIdx.x + w];
            if (lexless(ov, oi, rv[threadIdx.x], ri[threadIdx.x])) {
                rv[threadIdx.x] = ov; ri[threadIdx.x] = oi;
            }
        }
        __syncthreads();
    }
    if (threadIdx.x == 0) {
        priorcol[row] = ri[0];
        atomicAdd(&colsum[ri[0]], 1);
    }
}

// ---------------------------------------------------------------------------
// iterB: block per column; active iff colsum[j]==0. Argmin over UNINFLATED
// rows only (inflated rows strictly dominated: base <= ~10.2e3 < 1e5-50).
// rowiter < t  <=>  row matched before this iteration (inflated).
// ---------------------------------------------------------------------------
__global__ __launch_bounds__(256) void k_iterB(const float* __restrict__ pb,
        const float* __restrict__ gb, const int* __restrict__ glab,
        const float* __restrict__ clsval,
        const float4* __restrict__ pnorm, const float4* __restrict__ pinfo,
        const float4* __restrict__ gcb, const float4* __restrict__ gnm,
        const float* __restrict__ gar,
        int* __restrict__ rowiter, int* __restrict__ rowcnt,
        int* __restrict__ rowfirst, int* __restrict__ colsum,
        int* __restrict__ scal, int t)
{
    int j = blockIdx.x;
    if (colsum[j] != 0) return;
    if (threadIdx.x == 0) scal[S_BODY + t] = 1;   // body ran this iteration

    float4 g  = ((const float4*)gb)[j];
    float4 cb = gcb[j];
    float4 Gn = gnm[j];
    float  ga = gar[j];
    const float* clscol = clsval + (size_t)glab[j] * NP;
    const float4* pb4 = (const float4*)pb;

    __shared__ float rv[256]; __shared__ int ri[256];
    float best = FLT_MAX; int bi = 0x7fffffff;
    for (int i = threadIdx.x; i < NP; i += 256) {
        if (rowiter[i] < t) continue;   // inflated row: can never win
        float cc, iou;
        cost_iou(pb4[i], pnorm[i], pinfo[i], g, cb, Gn, ga, clscol[i], cc, iou);
        if (lexless(cc, i, best, bi)) { best = cc; bi = i; }
    }
    rv[threadIdx.x] = best; ri[threadIdx.x] = bi; __syncthreads();
    for (int w = 128; w > 0; w >>= 1) {
        if (threadIdx.x < (unsigned)w) {
            float ov = rv[threadIdx.x + w]; int oi = ri[threadIdx.x + w];
            if (lexless(ov, oi, rv[threadIdx.x], ri[threadIdx.x])) {
                rv[threadIdx.x] = ov; ri[threadIdx.x] = oi;
            }
        }
        __syncthreads();
    }
    if (threadIdx.x == 0) {
        int pos = ri[0];
        colsum[j] = 1;
        int old = atomicAdd(&rowcnt[pos], 1);
        if (old >= 1) scal[S_MULTI] = 1;   // same-iteration collision
        atomicMin(&rowfirst[pos], j);
        atomicMin(&rowiter[pos], t);       // matched at iteration t
    }
}

// ---------------------------------------------------------------------------
// iterC (m_fix): iff body ran at t && anymulti: each prior row re-argmins its
// inflated cost (exact sequential +1e5 per elapsed iteration).
// ---------------------------------------------------------------------------
__global__ __launch_bounds__(256) void k_iterC(const float* __restrict__ pb,
        const float* __restrict__ gb, const int* __restrict__ glab,
        const float* __restrict__ clsval,
        const float4* __restrict__ pnorm, const float4* __restrict__ pinfo,
        const float4* __restrict__ gcb, const float4* __restrict__ gnm,
        const float* __restrict__ gar,
        const int* __restrict__ plist, const int* __restrict__ rowiter,
        int* __restrict__ priorcol, int* __restrict__ colsum,
        int* __restrict__ scal, int t)
{
    if (scal[S_BODY + t] == 0 || scal[S_MULTI] == 0) return;
    if ((int)blockIdx.x >= scal[S_NPRI]) return;
    int row = plist[blockIdx.x];
    int k = t - rowiter[row]; if (k < 0) k = 0;   // prior rows: rowiter=-1 -> t+1
    float4 p = ((const float4*)pb)[row];
    float4 pn = pnorm[row];
    float4 pi4 = pinfo[row];

    __shared__ float rv[256]; __shared__ int ri[256];
    float best = FLT_MAX; int bj = 0x7fffffff;
    for (int j = threadIdx.x; j < NG; j += 256) {
        float cc, iou;
        cost_iou(p, pn, pi4, ((const float4*)gb)[j], gcb[j], gnm[j], gar[j],
                 clsval[(size_t)glab[j] * NP + row], cc, iou);
        float val = inflate(cc, k);
        if (lexless(val, j, best, bj)) { best = val; bj = j; }
    }
    rv[threadIdx.x] = best; ri[threadIdx.x] = bj; __syncthreads();
    for (int w = 128; w > 0; w >>= 1) {
        if (threadIdx.x < (unsigned)w) {
            float ov = rv[threadIdx.x + w]; int oi = ri[threadIdx.x + w];
            if (lexless(ov, oi, rv[threadIdx.x], ri[threadIdx.x])) {
                rv[threadIdx.x] = ov; ri[threadIdx.x] = oi;
            }
        }
        __syncthreads();
    }
    if (threadIdx.x == 0) {
        int nb = ri[0];
        int oldc = priorcol[row];
        if (nb != oldc) {
            atomicSub(&colsum[oldc], 1);
            atomicAdd(&colsum[nb], 1);
            priorcol[row] = nb;
        }
    }
}

// ---------------------------------------------------------------------------
// Final: fg = rowcnt>0; matched = priorcol (prior rows) else rowfirst. int32.
// ---------------------------------------------------------------------------
__global__ __launch_bounds__(256) void k_final(const int* __restrict__ rowcnt,
        const int* __restrict__ prior, const int* __restrict__ priorcol,
        const int* __restrict__ rowfirst, int* __restrict__ out)
{
    int i = blockIdx.x * 256 + threadIdx.x;
    if (i >= NP) return;
    int fg = rowcnt[i] > 0;
    out[i] = fg ? 1 : 0;
    out[NP + i] = fg ? (prior[i] ? priorcol[i] : rowfirst[i]) : 0;
}

extern "C" void kernel_launch(void* const* d_in, const int* in_sizes, int n_in,
                              void* d_out, int out_size, void* d_ws, size_t ws_size,
                              hipStream_t stream)
{
    (void)in_sizes; (void)n_in; (void)out_size; (void)ws_size;
    const float* logits = (const float*)d_in[0];
    const float* pboxes = (const float*)d_in[1];
    const float* gboxes = (const float*)d_in[2];
    const int*   glab   = (const int*)d_in[3];
    const int*   imgh   = (const int*)d_in[4];
    const int*   imgw   = (const int*)d_in[5];
    int* out = (int*)d_out;

    char* w = (char*)d_ws;
    float*  clsval  = (float*)(w);                    // 3,200,000
    float4* pnorm   = (float4*)(w + 3200000);         //   160,000
    float4* pinfo   = (float4*)(w + 3360000);         //   160,000
    float4* gcb     = (float4*)(w + 3520000);         //    16,000
    float4* gnm     = (float4*)(w + 3536000);         //    16,000
    float*  gar     = (float*)(w + 3552000);          //     4,000
    int* rowcnt     = (int*)(w + 3556000);            //    40,000
    int* rowfirst   = (int*)(w + 3596000);            //    40,000
    int* rowiter    = (int*)(w + 3636000);            //    40,000
    int* prior      = (int*)(w + 3676000);            //    40,000
    int* priorcol   = (int*)(w + 3716000);            //    40,000
    int* plist      = (int*)(w + 3756000);            //    40,000
    int* picks      = (int*)(w + 3796000);            //    20,000
    int* dkarr      = (int*)(w + 3816000);            //     4,000
    int* colsum     = (int*)(w + 3820000);            //     4,000
    int* scal       = (int*)(w + 3824000);            //       128
    float* pcv      = (float*)(w + 3824128);          //    40,000
    int*   pci      = (int*)(w + 3864128);            //    40,000
    float* piv      = (float*)(w + 3904128);          //    40,000

    hipLaunchKernelGGL(k_prep, dim3(2701), dim3(256), 0, stream,
                       logits, pboxes, gboxes, imgw, imgh,
                       clsval, pnorm, pinfo, gcb, gnm, gar,
                       rowcnt, rowfirst, rowiter, prior, priorcol, colsum, scal);
    hipLaunchKernelGGL(k_cost2, dim3(NG * NCH), dim3(256), 0, stream,
                       pboxes, gboxes, glab, clsval, pnorm, pinfo, gcb, gnm, gar,
                       pcv, pci, piv);
    hipLaunchKernelGGL(k_costmerge, dim3(4), dim3(256), 0, stream,
                       pcv, pci, piv, rowcnt, rowfirst, rowiter, picks, dkarr);
    hipLaunchKernelGGL(k_pscan, dim3(40), dim3(256), 0, stream,
                       rowcnt, prior, plist, scal);
    hipLaunchKernelGGL(k_pfixsurv, dim3(2504), dim3(256), 0, stream,
                       pboxes, gboxes, glab, clsval, pnorm, pinfo, gcb, gnm, gar,
                       plist, priorcol, colsum, scal, rowcnt, picks, dkarr);
    for (int t = 0; t < LMAX; t++) {
        hipLaunchKernelGGL(k_iterB, dim3(NG), dim3(256), 0, stream,
                           pboxes, gboxes, glab, clsval, pnorm, pinfo, gcb, gnm, gar,
                           rowiter, rowcnt, rowfirst, colsum, scal, t);
        hipLaunchKernelGGL(k_iterC, dim3(2500), dim3(256), 0, stream,
                           pboxes, gboxes, glab, clsval, pnorm, pinfo, gcb, gnm, gar,
                           plist, rowiter, priorcol, colsum, scal, t);
    }
    hipLaunchKernelGGL(k_final, dim3(40), dim3(256), 0, stream,
                       rowcnt, prior, priorcol, rowfirst, out);
}

// Round 10
// 191.744 us; speedup vs baseline: 4.2175x; 1.0364x over previous
//
#include <hip/hip_runtime.h>
#include <cfloat>
#include <cmath>

#define NP 10000
#define NG 1000
#define NC 80
#define LMAX 6
#define NCH 2
#define CHSZ (NP / NCH)
#define MAIN_IT 19          // 19*256 = 4864 uniform indices per 5000-chunk
#define TAIL_N  136         // remaining 136 indices

#define S_MULTI 12
#define S_BODY  16
#define RI_BIG  0x3fffffff
#define KMAX    0xFFFFFFFFFFFFFFFFull

__device__ __forceinline__ bool lexless(float av, int ai, float bv, int bi) {
    return (av < bv) || (av == bv && ai < bi);
}

// float -> order-preserving u32 (no NaNs in this data), packed with index.
// ascending u64 order == lexicographic (value asc, index asc).
__device__ __forceinline__ unsigned long long packkey(float v, int idx) {
    unsigned u = __float_as_uint(v);
    u ^= (unsigned)(((int)u) >> 31) | 0x80000000u;
    return ((unsigned long long)u << 32) | (unsigned)idx;
}
__device__ __forceinline__ int keyidx(unsigned long long k) {
    return (int)(unsigned)(k & 0xFFFFFFFFu);
}

// Exact sequential +1e5 inflation (reference adds 1e5 once per loop iter).
__device__ __forceinline__ float inflate(float c, int k) {
    for (int q = 0; q < k; q++) c += 100000.0f;
    return c;
}

// Per-pair cost+iou from precomputed tables. Contraction OFF so every kernel
// that recomputes cost(i,j) agrees bit-exactly.
__device__ __forceinline__ void cost_iou(float4 p, float4 pn, float4 pi,
        float4 g, float4 cb, float4 Gn, float ga, float clsv,
        float& cc_out, float& iou_out) {
#pragma clang fp contract(off)
    float wx = fminf(p.z, g.z) - fmaxf(p.x, g.x); wx = fmaxf(wx, 0.0f);
    float wy = fminf(p.w, g.w) - fmaxf(p.y, g.y); wy = fmaxf(wy, 0.0f);
    float inter = wx * wy;
    float uni = pi.z + ga - inter;
    float iou = inter / fmaxf(uni, 1e-12f);
    float ex = fmaxf(p.z, g.z) - fminf(p.x, g.x); ex = fmaxf(ex, 0.0f);
    float ey = fmaxf(p.w, g.w) - fminf(p.y, g.y); ey = fmaxf(ey, 0.0f);
    float enc = ex * ey;
    float giou = iou - (enc - uni) / fmaxf(enc, 1e-12f);
    float l1 = ((fabsf(pn.x - Gn.x) + fabsf(pn.y - Gn.y))
                + fabsf(pn.z - Gn.z)) + fabsf(pn.w - Gn.w);
    float cc = clsv + l1 * 5.0f;
    cc = cc + (-giou * 2.0f);
    bool inb = (pi.x > g.x && pi.x < g.z && pi.y > g.y && pi.y < g.w);
    bool inc = (pi.x > cb.x && pi.x < cb.z && pi.y > cb.y && pi.y < cb.w);
    cc = cc + ((inb && inc) ? 0.0f : 100.0f);
    cc = cc + pi.w;
    cc_out = cc; iou_out = iou;
}

// ---------------------------------------------------------------------------
// Fused prep. Block ranges:
//  [0,40): init state; [40,197): cls table; [197,201): per-gt tables;
//  [201,2701): wave-per-pred validity + per-pred tables
// ---------------------------------------------------------------------------
#define CLS_TI 64
#define PB_CLS0 40
#define PB_G0   197
#define PB_V0   201
__global__ __launch_bounds__(256) void k_prep(const float* __restrict__ logits,
        const float* __restrict__ pb, const float* __restrict__ gb,
        const int* __restrict__ imgw, const int* __restrict__ imgh,
        float* __restrict__ clsval, float4* __restrict__ pnorm,
        float4* __restrict__ pinfo, float4* __restrict__ gcb,
        float4* __restrict__ gnm, float* __restrict__ gar,
        int* rowcnt, int* rowfirst, int* rowiter, int* prior, int* priorcol,
        int* colsum, int* scal)
{
    __shared__ float sl[CLS_TI * (NC + 1)];
    int b = blockIdx.x;
    if (b < PB_CLS0) {
        int i = b * 256 + threadIdx.x;
        if (i < NP) {
            rowcnt[i] = 0; rowfirst[i] = 0x7fffffff; rowiter[i] = RI_BIG;
            prior[i] = 0; priorcol[i] = 0;
        }
        if (i < NG) colsum[i] = 0;
        if (i < 32) scal[i] = 0;
    } else if (b < PB_G0) {
        int i0 = (b - PB_CLS0) * CLS_TI;
        bool full = (i0 + CLS_TI) <= NP;
        if (full) {
            const float* src = logits + (size_t)i0 * NC;
            for (int e = threadIdx.x; e < CLS_TI * NC; e += 256) {
                int di = e / NC, c = e - di * NC;
                sl[di * (NC + 1) + c] = src[e];
            }
        } else {
            for (int e = threadIdx.x; e < CLS_TI * NC; e += 256) {
                int di = e / NC, c = e - di * NC;
                int i = i0 + di;
                sl[di * (NC + 1) + c] = (i < NP) ? logits[(size_t)i * NC + c] : 0.0f;
            }
        }
        __syncthreads();
        for (int e = threadIdx.x; e < CLS_TI * NC; e += 256) {
            int c = e >> 6, di = e & 63;
            int i = i0 + di;
            if (i >= NP) continue;
            float x = sl[di * (NC + 1) + c];
            float p = 1.0f / (1.0f + expf(-x));
            float neg = -log1pf(-(p - 1e-12f)) * 0.75f * (p * p);
            float om = 1.0f - p;
            float pos = -logf(p + 1e-12f) * 0.25f * (om * om);
            clsval[(size_t)c * NP + i] = (pos - neg) * 2.0f;   // * CLS_W
        }
    } else if (b < PB_V0) {
#pragma clang fp contract(off)
        int j = (b - PB_G0) * 256 + threadIdx.x;
        if (j < NG) {
            float fw = (float)imgw[0], fh = (float)imgh[0];
            float4 g = ((const float4*)gb)[j];
            float gcx = (g.x + g.z) * 0.5f, gcy = (g.y + g.w) * 0.5f;
            float gw = g.z - g.x, gh = g.w - g.y;
            float4 cb; cb.x = gcx - 2.5f * gw; cb.y = gcy - 2.5f * gh;
            cb.z = gcx + 2.5f * gw; cb.w = gcy + 2.5f * gh;
            gcb[j] = cb;
            float4 Gn; Gn.x = g.x / fw; Gn.y = g.y / fh; Gn.z = g.z / fw; Gn.w = g.w / fh;
            gnm[j] = Gn;
            gar[j] = (g.z - g.x) * (g.w - g.y);
        }
    } else {
#pragma clang fp contract(off)
        int wave = threadIdx.x >> 6;
        int lane = threadIdx.x & 63;
        int i = (b - PB_V0) * 4 + wave;
        if (i >= NP) return;
        float4 p = ((const float4*)pb)[i];
        float pcx = (p.x + p.z) * 0.5f, pcy = (p.y + p.w) * 0.5f;
        int vb = 0, vc = 0;
        const float4* gb4 = (const float4*)gb;
        for (int j = lane; j < NG; j += 64) {
            float4 g = gb4[j];
            vb |= (pcx > g.x && pcx < g.z && pcy > g.y && pcy < g.w) ? 1 : 0;
            float gcx = (g.x + g.z) * 0.5f, gcy = (g.y + g.w) * 0.5f;
            float gw = g.z - g.x, gh = g.w - g.y;
            vc |= (pcx > gcx - 2.5f * gw && pcx < gcx + 2.5f * gw &&
                   pcy > gcy - 2.5f * gh && pcy < gcy + 2.5f * gh) ? 1 : 0;
        }
        int any = (__any(vb) ? 1 : 0) | (__any(vc) ? 1 : 0);
        if (lane == 0) {
            float fw = (float)imgw[0], fh = (float)imgh[0];
            float4 pn; pn.x = p.x / fw; pn.y = p.y / fh; pn.z = p.z / fw; pn.w = p.w / fh;
            pnorm[i] = pn;
            float4 pi4; pi4.x = pcx; pi4.y = pcy;
            pi4.z = (p.z - p.x) * (p.w - p.y);
            pi4.w = any ? 0.0f : 10000.0f;
            pinfo[i] = pi4;
        }
    }
}

// ---------------------------------------------------------------------------
// Shared tree merge: per-thread sorted lists (5 slots + sentinel, stride 7)
// of u64 cost keys (asc) and float ious (desc) -> merged top-5 in slots 0..4.
// ---------------------------------------------------------------------------
__device__ void tree_merge(unsigned long long* s_k, float* s_iv, int tid) {
    __syncthreads();
    for (int w = 128; w > 0; w >>= 1) {
        if (tid < w) {
            int a = tid * 7, bb = (tid + w) * 7;
            unsigned long long ok[5]; float og[5];
            int pa = a, pbp = bb;
#pragma unroll
            for (int t = 0; t < 5; t++) {
                unsigned long long A = s_k[pa], B = s_k[pbp];
                if (A <= B) { ok[t] = A; pa++; } else { ok[t] = B; pbp++; }
            }
            int qa = a, qb = bb;
#pragma unroll
            for (int t = 0; t < 5; t++) {
                float A = s_iv[qa], B = s_iv[qb];
                if (A >= B) { og[t] = A; qa++; } else { og[t] = B; qb++; }
            }
#pragma unroll
            for (int t = 0; t < 5; t++) { s_k[a+t] = ok[t]; s_iv[a+t] = og[t]; }
        }
        __syncthreads();
    }
}

// ---------------------------------------------------------------------------
// k_cost2: block (j, chunk c). Branchless per-thread TOP-2 (u64 cost key,
// float iou) over a constant-trip main loop (19 iters) + tail, tree-merged;
// exactness guaranteed by detection + rare exact-top-5 fallback re-scan:
// block top-5 is within the union of per-thread top-2 unless some thread
// holds >=3 of the true top-5, detectable as (thread 2nd best beats merged
// 5th) -- conservative, fires ~4% of blocks.
// ---------------------------------------------------------------------------
__global__ __launch_bounds__(256) void k_cost2(
        const float* __restrict__ pb, const float* __restrict__ gb,
        const int* __restrict__ glab, const float* __restrict__ clsval,
        const float4* __restrict__ pnorm, const float4* __restrict__ pinfo,
        const float4* __restrict__ gcb, const float4* __restrict__ gnm,
        const float* __restrict__ gar,
        unsigned long long* __restrict__ pck, float* __restrict__ piv)
{
    __shared__ unsigned long long s_k[256 * 7];
    __shared__ float s_iv[256 * 7];
    __shared__ int s_bad;

    int j = blockIdx.x >> 1;
    int c = blockIdx.x & 1;
    int tid = threadIdx.x;
    if (tid == 0) s_bad = 0;
    float4 g  = ((const float4*)gb)[j];
    float4 cb = gcb[j];
    float4 Gn = gnm[j];
    float  ga = gar[j];
    const float* clscol = clsval + (size_t)glab[j] * NP;
    const float4* pb4 = (const float4*)pb;
    int base_i = c * CHSZ;

    // ---- main pass: branchless top-2 ----
    unsigned long long k0 = KMAX, k1 = KMAX;   // 2 smallest cost keys
    float i0 = -1.0f, i1 = -1.0f;              // 2 largest ious
#pragma unroll 4
    for (int k = 0; k < MAIN_IT; k++) {
        int i = base_i + tid + k * 256;
        float cc, iou;
        cost_iou(pb4[i], pnorm[i], pinfo[i], g, cb, Gn, ga, clscol[i], cc, iou);
        unsigned long long key = packkey(cc, i);
        unsigned long long mx = (k0 > key) ? k0 : key;
        k0 = (k0 > key) ? key : k0;
        k1 = (k1 > mx) ? mx : k1;
        float mnv = fminf(i0, iou);
        i0 = fmaxf(i0, iou);
        i1 = fmaxf(i1, mnv);
    }
    if (tid < TAIL_N) {
        int i = base_i + MAIN_IT * 256 + tid;
        float cc, iou;
        cost_iou(pb4[i], pnorm[i], pinfo[i], g, cb, Gn, ga, clscol[i], cc, iou);
        unsigned long long key = packkey(cc, i);
        unsigned long long mx = (k0 > key) ? k0 : key;
        k0 = (k0 > key) ? key : k0;
        k1 = (k1 > mx) ? mx : k1;
        float mnv = fminf(i0, iou);
        i0 = fmaxf(i0, iou);
        i1 = fmaxf(i1, mnv);
    }

    int base = tid * 7;
    s_k[base+0] = k0; s_k[base+1] = k1;
    s_k[base+2] = KMAX; s_k[base+3] = KMAX; s_k[base+4] = KMAX; s_k[base+5] = KMAX;
    s_iv[base+0] = i0; s_iv[base+1] = i1;
    s_iv[base+2] = -2.0f; s_iv[base+3] = -2.0f; s_iv[base+4] = -2.0f; s_iv[base+5] = -2.0f;

    tree_merge(s_k, s_iv, tid);

    // ---- exactness detection ----
    unsigned long long m5 = s_k[4];
    float m5i = s_iv[4];
    if (k1 < m5 || i1 > m5i) s_bad = 1;
    __syncthreads();

    if (s_bad) {
        // ---- exact fallback: full top-5 maintenance (cold) ----
        unsigned long long kv[5]; float iv[5];
#pragma unroll
        for (int t = 0; t < 5; t++) { kv[t] = KMAX; iv[t] = -1.0f; }
        for (int k = 0; k <= MAIN_IT; k++) {
            int i = base_i + tid + k * 256;
            if (k == MAIN_IT && tid >= TAIL_N) break;
            float cc, iou;
            cost_iou(pb4[i], pnorm[i], pinfo[i], g, cb, Gn, ga, clscol[i], cc, iou);
            unsigned long long key = packkey(cc, i);
            if (key < kv[4]) {
                kv[4] = key;
#pragma unroll
                for (int t = 4; t > 0; t--)
                    if (kv[t] < kv[t-1]) { unsigned long long tv = kv[t]; kv[t] = kv[t-1]; kv[t-1] = tv; }
            }
            if (iou > iv[4]) {
                iv[4] = iou;
#pragma unroll
                for (int t = 4; t > 0; t--)
                    if (iv[t] > iv[t-1]) { float tv = iv[t]; iv[t] = iv[t-1]; iv[t-1] = tv; }
            }
        }
#pragma unroll
        for (int t = 0; t < 5; t++) { s_k[base+t] = kv[t]; s_iv[base+t] = iv[t]; }
        s_k[base+5] = KMAX; s_iv[base+5] = -2.0f;
        tree_merge(s_k, s_iv, tid);
    }

    if (tid == 0) {
        int ob = blockIdx.x * 5;
#pragma unroll
        for (int t = 0; t < 5; t++) { pck[ob + t] = s_k[t]; piv[ob + t] = s_iv[t]; }
    }
}

// ---------------------------------------------------------------------------
// Merge partials: thread per gt. Exact 2-way merge of sorted 5-lists.
// dk (trunc of descending-order iou sum), picks, row atomics.
// ---------------------------------------------------------------------------
__global__ __launch_bounds__(256) void k_costmerge(
        const unsigned long long* __restrict__ pck, const float* __restrict__ piv,
        int* __restrict__ rowcnt, int* __restrict__ rowfirst,
        int* __restrict__ rowiter, int* __restrict__ picks,
        int* __restrict__ dkarr)
{
    int j = blockIdx.x * 256 + threadIdx.x;
    if (j >= NG) return;
    int base = j * 2 * 5;
    int h0 = 0, h1 = 0;
    int besti[5];
#pragma unroll
    for (int r = 0; r < 5; r++) {
        unsigned long long v0 = pck[base + h0];
        unsigned long long v1 = pck[base + 5 + h1];
        if (v0 <= v1) { besti[r] = keyidx(v0); h0++; }
        else          { besti[r] = keyidx(v1); h1++; }
    }
    int g0 = 0, g1 = 0;
    float ivm[5];
#pragma unroll
    for (int r = 0; r < 5; r++) {
        float v0 = piv[base + g0];
        float v1 = piv[base + 5 + g1];
        if (v0 >= v1) { ivm[r] = v0; g0++; } else { ivm[r] = v1; g1++; }
    }
    float s = (((ivm[0] + ivm[1]) + ivm[2]) + ivm[3]) + ivm[4];
    int dk = (int)s;                 // astype(int32): truncation
    if (dk < 1) dk = 1;
    dkarr[j] = dk;
    for (int t = 0; t < dk; t++) {
        int r = besti[t];
        picks[j * 5 + t] = r;
        atomicAdd(&rowcnt[r], 1);
        atomicMin(&rowfirst[r], j);
        atomicMin(&rowiter[r], -1);   // initially matched
    }
}

// ---------------------------------------------------------------------------
// Fused prior-detect + pfix + surv (no plist/pscan).
// Blocks [0,2500): rows 4b..4b+3; rows with rowcnt>1 -> prior=1 and
// cooperative argmin over 1000 gts -> priorcol, colsum++.
// Blocks [2500,2504): surviving single-pick rows -> colsum.
// ---------------------------------------------------------------------------
__global__ __launch_bounds__(256) void k_pfixsurv(const float* __restrict__ pb,
        const float* __restrict__ gb, const int* __restrict__ glab,
        const float* __restrict__ clsval,
        const float4* __restrict__ pnorm, const float4* __restrict__ pinfo,
        const float4* __restrict__ gcb, const float4* __restrict__ gnm,
        const float* __restrict__ gar,
        int* __restrict__ prior, int* __restrict__ priorcol,
        int* __restrict__ colsum,
        const int* __restrict__ rowcnt, const int* __restrict__ picks,
        const int* __restrict__ dkarr)
{
    int b = blockIdx.x;
    int tid = threadIdx.x;
    if (b >= 2500) {
        int j = (b - 2500) * 256 + tid;
        if (j >= NG) return;
        int c = 0;
        int dk = dkarr[j];
        for (int t = 0; t < dk; t++) if (rowcnt[picks[j * 5 + t]] == 1) c++;
        if (c) atomicAdd(&colsum[j], c);
        return;
    }
    __shared__ float rv[256]; __shared__ int ri[256];
    for (int q = 0; q < 4; q++) {
        int row = b * 4 + q;
        if (rowcnt[row] <= 1) continue;      // uniform across block
        if (tid == 0) prior[row] = 1;
        float4 p = ((const float4*)pb)[row];
        float4 pn = pnorm[row];
        float4 pi4 = pinfo[row];
        float best = FLT_MAX; int bj = 0x7fffffff;
        for (int j = tid; j < NG; j += 256) {
            float cc, iou;
            cost_iou(p, pn, pi4, ((const float4*)gb)[j], gcb[j], gnm[j], gar[j],
                     clsval[(size_t)glab[j] * NP + row], cc, iou);
            if (lexless(cc, j, best, bj)) { best = cc; bj = j; }
        }
        rv[tid] = best; ri[tid] = bj; __syncthreads();
        for (int w = 128; w > 0; w >>= 1) {
            if (tid < w) {
                float ov = rv[tid + w]; int oi = ri[tid + w];
                if (lexless(ov, oi, rv[tid], ri[tid])) { rv[tid] = ov; ri[tid] = oi; }
            }
            __syncthreads();
        }
        if (tid == 0) {
            priorcol[row] = ri[0];
            atomicAdd(&colsum[ri[0]], 1);
        }
        __syncthreads();
    }
}

// ---------------------------------------------------------------------------
// iterB: block per column; active iff colsum[j]==0. Argmin over UNINFLATED
// rows only (inflated strictly dominated). rowiter < t <=> inflated.
// ---------------------------------------------------------------------------
__global__ __launch_bounds__(256) void k_iterB(const float* __restrict__ pb,
        const float* __restrict__ gb, const int* __restrict__ glab,
        const float* __restrict__ clsval,
        const float4* __restrict__ pnorm, const float4* __restrict__ pinfo,
        const float4* __restrict__ gcb, const float4* __restrict__ gnm,
        const float* __restrict__ gar,
        int* __restrict__ rowiter, int* __restrict__ rowcnt,
        int* __restrict__ rowfirst, int* __restrict__ colsum,
        int* __restrict__ scal, int t)
{
    int j = blockIdx.x;
    if (colsum[j] != 0) return;
    if (threadIdx.x == 0) scal[S_BODY + t] = 1;

    float4 g  = ((const float4*)gb)[j];
    float4 cb = gcb[j];
    float4 Gn = gnm[j];
    float  ga = gar[j];
    const float* clscol = clsval + (size_t)glab[j] * NP;
    const float4* pb4 = (const float4*)pb;

    __shared__ float rv[256]; __shared__ int ri[256];
    float best = FLT_MAX; int bi = 0x7fffffff;
    for (int i = threadIdx.x; i < NP; i += 256) {
        if (rowiter[i] < t) continue;
        float cc, iou;
        cost_iou(pb4[i], pnorm[i], pinfo[i], g, cb, Gn, ga, clscol[i], cc, iou);
        if (lexless(cc, i, best, bi)) { best = cc; bi = i; }
    }
    rv[threadIdx.x] = best; ri[threadIdx.x] = bi; __syncthreads();
    for (int w = 128; w > 0; w >>= 1) {
        if (threadIdx.x < (unsigned)w) {
            float ov = rv[threadIdx.x + w]; int oi = ri[threadIdx.x + w];
            if (lexless(ov, oi, rv[threadIdx.x], ri[threadIdx.x])) {
                rv[threadIdx.x] = ov; ri[threadIdx.x] = oi;
            }
        }
        __syncthreads();
    }
    if (threadIdx.x == 0) {
        int pos = ri[0];
        colsum[j] = 1;
        int old = atomicAdd(&rowcnt[pos], 1);
        if (old >= 1) scal[S_MULTI] = 1;
        atomicMin(&rowfirst[pos], j);
        atomicMin(&rowiter[pos], t);
    }
}

// ---------------------------------------------------------------------------
// iterC (m_fix): iff body ran at t && anymulti: prior rows (scanned directly,
// 4 rows/block) re-argmin their inflated cost (exact sequential +1e5).
// ---------------------------------------------------------------------------
__global__ __launch_bounds__(256) void k_iterC(const float* __restrict__ pb,
        const float* __restrict__ gb, const int* __restrict__ glab,
        const float* __restrict__ clsval,
        const float4* __restrict__ pnorm, const float4* __restrict__ pinfo,
        const float4* __restrict__ gcb, const float4* __restrict__ gnm,
        const float* __restrict__ gar,
        const int* __restrict__ prior, const int* __restrict__ rowiter,
        int* __restrict__ priorcol, int* __restrict__ colsum,
        int* __restrict__ scal, int t)
{
    if (scal[S_BODY + t] == 0 || scal[S_MULTI] == 0) return;
    int b = blockIdx.x;
    int tid = threadIdx.x;
    __shared__ float rv[256]; __shared__ int ri[256];
    for (int q = 0; q < 4; q++) {
        int row = b * 4 + q;
        if (!prior[row]) continue;           // uniform across block
        int k = t - rowiter[row]; if (k < 0) k = 0;   // prior rows: -1 -> t+1
        float4 p = ((const float4*)pb)[row];
        float4 pn = pnorm[row];
        float4 pi4 = pinfo[row];
        float best = FLT_MAX; int bj = 0x7fffffff;
        for (int j = tid; j < NG; j += 256) {
            float cc, iou;
            cost_iou(p, pn, pi4, ((const float4*)gb)[j], gcb[j], gnm[j], gar[j],
                     clsval[(size_t)glab[j] * NP + row], cc, iou);
            float val = inflate(cc, k);
            if (lexless(val, j, best, bj)) { best = val; bj = j; }
        }
        rv[tid] = best; ri[tid] = bj; __syncthreads();
        for (int w = 128; w > 0; w >>= 1) {
            if (tid < w) {
                float ov = rv[tid + w]; int oi = ri[tid + w];
                if (lexless(ov, oi, rv[tid], ri[tid])) { rv[tid] = ov; ri[tid] = oi; }
            }
            __syncthreads();
        }
        if (tid == 0) {
            int nb = ri[0];
            int oldc = priorcol[row];
            if (nb != oldc) {
                atomicSub(&colsum[oldc], 1);
                atomicAdd(&colsum[nb], 1);
                priorcol[row] = nb;
            }
        }
        __syncthreads();
    }
}

// ---------------------------------------------------------------------------
// Final: fg = rowcnt>0; matched = priorcol (prior rows) else rowfirst. int32.
// ---------------------------------------------------------------------------
__global__ __launch_bounds__(256) void k_final(const int* __restrict__ rowcnt,
        const int* __restrict__ prior, const int* __restrict__ priorcol,
        const int* __restrict__ rowfirst, int* __restrict__ out)
{
    int i = blockIdx.x * 256 + threadIdx.x;
    if (i >= NP) return;
    int fg = rowcnt[i] > 0;
    out[i] = fg ? 1 : 0;
    out[NP + i] = fg ? (prior[i] ? priorcol[i] : rowfirst[i]) : 0;
}

extern "C" void kernel_launch(void* const* d_in, const int* in_sizes, int n_in,
                              void* d_out, int out_size, void* d_ws, size_t ws_size,
                              hipStream_t stream)
{
    (void)in_sizes; (void)n_in; (void)out_size; (void)ws_size;
    const float* logits = (const float*)d_in[0];
    const float* pboxes = (const float*)d_in[1];
    const float* gboxes = (const float*)d_in[2];
    const int*   glab   = (const int*)d_in[3];
    const int*   imgh   = (const int*)d_in[4];
    const int*   imgw   = (const int*)d_in[5];
    int* out = (int*)d_out;

    char* w = (char*)d_ws;
    float*  clsval  = (float*)(w);                    // 3,200,000
    float4* pnorm   = (float4*)(w + 3200000);         //   160,000
    float4* pinfo   = (float4*)(w + 3360000);         //   160,000
    float4* gcb     = (float4*)(w + 3520000);         //    16,000
    float4* gnm     = (float4*)(w + 3536000);         //    16,000
    float*  gar     = (float*)(w + 3552000);          //     4,000
    int* rowcnt     = (int*)(w + 3556000);            //    40,000
    int* rowfirst   = (int*)(w + 3596000);            //    40,000
    int* rowiter    = (int*)(w + 3636000);            //    40,000
    int* prior      = (int*)(w + 3676000);            //    40,000
    int* priorcol   = (int*)(w + 3716000);            //    40,000
    int* picks      = (int*)(w + 3756000);            //    20,000
    int* dkarr      = (int*)(w + 3776000);            //     4,000
    int* colsum     = (int*)(w + 3780000);            //     4,000
    int* scal       = (int*)(w + 3784000);            //       128
    unsigned long long* pck = (unsigned long long*)(w + 3784128); // 80,000
    float* piv      = (float*)(w + 3864128);          //    40,000

    hipLaunchKernelGGL(k_prep, dim3(2701), dim3(256), 0, stream,
                       logits, pboxes, gboxes, imgw, imgh,
                       clsval, pnorm, pinfo, gcb, gnm, gar,
                       rowcnt, rowfirst, rowiter, prior, priorcol, colsum, scal);
    hipLaunchKernelGGL(k_cost2, dim3(NG * NCH), dim3(256), 0, stream,
                       pboxes, gboxes, glab, clsval, pnorm, pinfo, gcb, gnm, gar,
                       pck, piv);
    hipLaunchKernelGGL(k_costmerge, dim3(4), dim3(256), 0, stream,
                       pck, piv, rowcnt, rowfirst, rowiter, picks, dkarr);
    hipLaunchKernelGGL(k_pfixsurv, dim3(2504), dim3(256), 0, stream,
                       pboxes, gboxes, glab, clsval, pnorm, pinfo, gcb, gnm, gar,
                       prior, priorcol, colsum, rowcnt, picks, dkarr);
    for (int t = 0; t < LMAX; t++) {
        hipLaunchKernelGGL(k_iterB, dim3(NG), dim3(256), 0, stream,
                           pboxes, gboxes, glab, clsval, pnorm, pinfo, gcb, gnm, gar,
                           rowiter, rowcnt, rowfirst, colsum, scal, t);
        hipLaunchKernelGGL(k_iterC, dim3(2500), dim3(256), 0, stream,
                           pboxes, gboxes, glab, clsval, pnorm, pinfo, gcb, gnm, gar,
                           prior, rowiter, priorcol, colsum, scal, t);
    }
    hipLaunchKernelGGL(k_final, dim3(40), dim3(256), 0, stream,
                       rowcnt, prior, priorcol, rowfirst, out);
}